// Round 6
// baseline (609.703 us; speedup 1.0000x reference)
//
#include <hip/hip_runtime.h>
#include <stdint.h>

#define B_   4
#define S_   2048
#define DI   1024
#define DOUT 1024
#define NHD  16
#define HD   64

typedef __attribute__((ext_vector_type(8))) short short8;
typedef __attribute__((ext_vector_type(4))) float f32x4;
typedef __attribute__((ext_vector_type(16))) float f32x16;

__device__ __forceinline__ unsigned short f32_bf16(float f) {
  union { float f; unsigned u; } v; v.f = f;
  unsigned r = v.u + 0x7FFFu + ((v.u >> 16) & 1u);   // RNE
  return (unsigned short)(r >> 16);
}

__device__ __forceinline__ unsigned pack_bf16x2(float a, float b) {
  union { float f; unsigned u; } x, y; x.f = a; y.f = b;
  return ((y.u + 0x8000u) & 0xFFFF0000u) | ((x.u + 0x8000u) >> 16);
}

// async 16B global->LDS (dst wave-uniform; HW adds lane*16)
__device__ __forceinline__ void gl_lds16(const void* g, void* s) {
  __builtin_amdgcn_global_load_lds(
      (const __attribute__((address_space(1))) unsigned int*)g,
      (__attribute__((address_space(3))) unsigned int*)s, 16, 0, 0);
}

#define EXP2(x) __builtin_amdgcn_exp2f(x)

// ---------- elementwise fp32 -> bf16 ----------
__global__ __launch_bounds__(256) void cvt_kernel(const float* __restrict__ src,
                                                  unsigned short* __restrict__ dst, int n4) {
  int i = blockIdx.x * blockDim.x + threadIdx.x;
  if (i < n4) {
    float4 v = ((const float4*)src)[i];
    ushort4 o;
    o.x = f32_bf16(v.x); o.y = f32_bf16(v.y); o.z = f32_bf16(v.z); o.w = f32_bf16(v.w);
    ((ushort4*)dst)[i] = o;
  }
}

// ---------- weight transpose+convert: W[k][n] f32 -> Wt[n][k] bf16 ----------
__global__ __launch_bounds__(256) void wtrans_kernel(const float* __restrict__ W,
                                                     unsigned short* __restrict__ Wt) {
  __shared__ __attribute__((aligned(16))) float tile[64][65];
  const int k0 = blockIdx.y * 64;
  const int n0 = blockIdx.x * 64;
  const int tid = threadIdx.x;
#pragma unroll
  for (int i = 0; i < 4; i++) {
    int c = tid + i * 256;
    int r = c >> 4;
    int cc = (c & 15) * 4;
    float4 v = *(const float4*)(W + (size_t)(k0 + r) * DOUT + n0 + cc);
    tile[r][cc] = v.x; tile[r][cc + 1] = v.y; tile[r][cc + 2] = v.z; tile[r][cc + 3] = v.w;
  }
  __syncthreads();
#pragma unroll
  for (int i = 0; i < 4; i++) {
    int c = tid + i * 256;
    int r = c >> 4;
    int cc = (c & 15) * 4;
    ushort4 o;
    o.x = f32_bf16(tile[cc + 0][r]);
    o.y = f32_bf16(tile[cc + 1][r]);
    o.z = f32_bf16(tile[cc + 2][r]);
    o.w = f32_bf16(tile[cc + 3][r]);
    *(ushort4*)(Wt + (size_t)(n0 + r) * DI + k0 + cc) = o;
  }
}

// ---------- V transpose: Vb[bh][s][hd] -> Vt[bh][hd][s] (bf16) ----------
__global__ __launch_bounds__(256) void vtrans_kernel(const unsigned short* __restrict__ Vb,
                                                     unsigned short* __restrict__ Vt) {
  __shared__ __attribute__((aligned(16))) unsigned short tile[64][72];
  const int bh = blockIdx.y;
  const int s0 = blockIdx.x * 64;
  const int tid = threadIdx.x;
  const unsigned short* src = Vb + (size_t)bh * S_ * HD + (size_t)s0 * HD;
#pragma unroll
  for (int i = 0; i < 2; i++) {
    int c = tid + i * 256;
    int r = c >> 3;
    int cc = (c & 7) * 8;
    *(uint4*)(&tile[r][cc]) = *(const uint4*)(src + r * HD + cc);
  }
  __syncthreads();
  unsigned short* dst = Vt + (size_t)bh * HD * S_ + s0;
#pragma unroll
  for (int i = 0; i < 2; i++) {
    int c = tid + i * 256;
    int r = c >> 3;
    int cc = (c & 7) * 8;
    union { unsigned short u[8]; uint4 v; } t;
#pragma unroll
    for (int j = 0; j < 8; j++) t.u[j] = tile[cc + j][r];
    *(uint4*)(dst + (size_t)r * S_ + cc) = t.v;
  }
}

// ---------- GEMM (m97 recipe). MODE 0: fused QKV (N=3072) scatter to head-major.
// MODE 1: fp32 row-major + bias. ----------
template <int MODE>
__global__ __launch_bounds__(256) void gemm_kernel(
    const unsigned short* __restrict__ A,
    const unsigned short* __restrict__ Bt,
    unsigned short* __restrict__ oQ,
    unsigned short* __restrict__ oK,
    unsigned short* __restrict__ oV,
    float* __restrict__ outF,
    const float* __restrict__ bias,
    int M, int N, int K) {
  __shared__ __attribute__((aligned(16))) unsigned short Asm_[128 * 32];
  __shared__ __attribute__((aligned(16))) unsigned short Bsm_[128 * 32];
  const int tid = threadIdx.x;
  const int lane = tid & 63;
  const int w = tid >> 6;
  const int wm = w >> 1, wn = w & 1;
  const int quad = lane >> 4, l16 = lane & 15;
  const int m0 = blockIdx.x * 128;
  const int n0 = blockIdx.y * 128;

  const int lr = lane >> 2;
  const int lc8 = (lane & 3) * 8;
  const unsigned short* gA0 = A + (size_t)(m0 + w * 32 + lr) * K + lc8;
  const unsigned short* gA1 = gA0 + (size_t)16 * K;
  const unsigned short* gB0 = Bt + (size_t)(n0 + w * 32 + lr) * K + lc8;
  const unsigned short* gB1 = gB0 + (size_t)16 * K;
  unsigned short* sA0 = Asm_ + (w * 2 + 0) * 512;
  unsigned short* sA1 = Asm_ + (w * 2 + 1) * 512;
  unsigned short* sB0 = Bsm_ + (w * 2 + 0) * 512;
  unsigned short* sB1 = Bsm_ + (w * 2 + 1) * 512;

  f32x4 acc[4][4] = {};

  for (int k0 = 0; k0 < K; k0 += 32) {
    __syncthreads();
    gl_lds16(gA0 + k0, sA0);
    gl_lds16(gA1 + k0, sA1);
    gl_lds16(gB0 + k0, sB0);
    gl_lds16(gB1 + k0, sB1);
    __syncthreads();
    short8 af[4], bfr[4];
#pragma unroll
    for (int mi = 0; mi < 4; mi++)
      af[mi] = *(const short8*)(Asm_ + (wm * 64 + mi * 16 + l16) * 32 + quad * 8);
#pragma unroll
    for (int ni = 0; ni < 4; ni++)
      bfr[ni] = *(const short8*)(Bsm_ + (wn * 64 + ni * 16 + l16) * 32 + quad * 8);
#pragma unroll
    for (int mi = 0; mi < 4; mi++)
#pragma unroll
      for (int ni = 0; ni < 4; ni++)
        acc[mi][ni] = __builtin_amdgcn_mfma_f32_16x16x32_bf16(af[mi], bfr[ni], acc[mi][ni], 0, 0, 0);
  }

  unsigned short* dst0 = nullptr;
  if (MODE == 0) {
    const int which = n0 >> 10;                 // block-uniform: 0=Q,1=K,2=V
    dst0 = which == 0 ? oQ : which == 1 ? oK : oV;
  }
#pragma unroll
  for (int mi = 0; mi < 4; mi++) {
#pragma unroll
    for (int ni = 0; ni < 4; ni++) {
      const int col = n0 + wn * 64 + ni * 16 + l16;
      float bv = (MODE == 1) ? bias[col] : 0.f;
#pragma unroll
      for (int r = 0; r < 4; r++) {
        const int row = m0 + wm * 64 + mi * 16 + quad * 4 + r;
        if (MODE == 0) {
          int b = row >> 11, s = row & 2047;
          int h = (col >> 6) & 15, hd = col & 63;
          dst0[(((size_t)(b * NHD + h)) * S_ + s) * HD + hd] = f32_bf16(acc[mi][ni][r]);
        } else {
          outF[(size_t)row * N + col] = acc[mi][ni][r] + bv;
        }
      }
    }
  }
}

// ================= flash attention helpers =================
__device__ __forceinline__ void softmax_tile(f32x16 (&s)[2], float& m_run, float& l_run,
                                             f32x16 (&oacc)[2], bool diag,
                                             int qrow, int k0, int h) {
  const float scl = 0.18033688f;   // (1/sqrt(64)) * log2(e)
  if (diag) {
#pragma unroll
    for (int mi = 0; mi < 2; mi++)
#pragma unroll
      for (int e = 0; e < 16; e++) {
        int key = k0 + mi * 32 + (e & 3) + 8 * (e >> 2) + 4 * h;
        if (key > qrow) s[mi][e] = -__builtin_inff();
      }
  }
  float vmax = -__builtin_inff();
#pragma unroll
  for (int mi = 0; mi < 2; mi++)
#pragma unroll
    for (int e = 0; e < 16; e++) vmax = fmaxf(vmax, s[mi][e]);
  vmax = fmaxf(vmax, __shfl_xor(vmax, 32));
  const float mnew = fmaxf(m_run, vmax * scl);
  const float alpha = EXP2(m_run - mnew);
  m_run = mnew;
  float rs = 0.f;
#pragma unroll
  for (int mi = 0; mi < 2; mi++)
#pragma unroll
    for (int e = 0; e < 16; e++) {
      float p = EXP2(fmaf(s[mi][e], scl, -mnew));
      s[mi][e] = p;
      rs += p;
    }
  rs += __shfl_xor(rs, 32);
  l_run = l_run * alpha + rs;
  oacc[0] *= alpha;
  oacc[1] *= alpha;
}

// combined softmax over a 128-key pair (two sacc sets), ONE merge
__device__ __forceinline__ void softmax_pair(f32x16 (&s0)[2], f32x16 (&s1)[2],
                                             float& m_run, float& l_run,
                                             f32x16 (&oacc)[2], bool diag1,
                                             int qrow, int k1, int h) {
  const float scl = 0.18033688f;
  if (diag1) {
#pragma unroll
    for (int mi = 0; mi < 2; mi++)
#pragma unroll
      for (int e = 0; e < 16; e++) {
        int key = k1 + mi * 32 + (e & 3) + 8 * (e >> 2) + 4 * h;
        if (key > qrow) s1[mi][e] = -__builtin_inff();
      }
  }
  float vmax = -__builtin_inff();
#pragma unroll
  for (int mi = 0; mi < 2; mi++)
#pragma unroll
    for (int e = 0; e < 16; e++) {
      vmax = fmaxf(vmax, s0[mi][e]);
      vmax = fmaxf(vmax, s1[mi][e]);
    }
  vmax = fmaxf(vmax, __shfl_xor(vmax, 32));
  const float mnew = fmaxf(m_run, vmax * scl);
  const float alpha = EXP2(m_run - mnew);
  m_run = mnew;
  float rs = 0.f;
#pragma unroll
  for (int mi = 0; mi < 2; mi++)
#pragma unroll
    for (int e = 0; e < 16; e++) {
      float p0 = EXP2(fmaf(s0[mi][e], scl, -mnew));
      float p1 = EXP2(fmaf(s1[mi][e], scl, -mnew));
      s0[mi][e] = p0;
      s1[mi][e] = p1;
      rs += p0 + p1;
    }
  rs += __shfl_xor(rs, 32);
  l_run = l_run * alpha + rs;
  oacc[0] *= alpha;
  oacc[1] *= alpha;
}

__device__ __forceinline__ void pv_tile(const f32x16 (&s)[2], f32x16 (&oacc)[2],
                                        const short8 (&vf)[4][2],
                                        unsigned short* myP, int l32, int h) {
#pragma unroll
  for (int mi = 0; mi < 2; mi++)
#pragma unroll
    for (int g2 = 0; g2 < 4; g2++) {
      uint2 pk;
      pk.x = pack_bf16x2(s[mi][4 * g2 + 0], s[mi][4 * g2 + 1]);
      pk.y = pack_bf16x2(s[mi][4 * g2 + 2], s[mi][4 * g2 + 3]);
      *(uint2*)(myP + l32 * 72 + mi * 32 + g2 * 8 + h * 4) = pk;
    }
#pragma unroll
  for (int ks2 = 0; ks2 < 4; ks2++) {
    short8 pf = *(const short8*)(myP + l32 * 72 + ks2 * 16 + h * 8);
#pragma unroll
    for (int mi2 = 0; mi2 < 2; mi2++)
      oacc[mi2] = __builtin_amdgcn_mfma_f32_32x32x16_bf16(vf[ks2][mi2], pf, oacc[mi2], 0, 0, 0);
  }
}

__device__ __forceinline__ void store_chunk(const f32x16 (&o)[2], float l_run, int qc,
                                            unsigned short* myP, unsigned short* ctx,
                                            int bh, int lane, int l32, int h) {
  const float inv = 1.f / l_run;
#pragma unroll
  for (int mi2 = 0; mi2 < 2; mi2++)
#pragma unroll
    for (int g2 = 0; g2 < 4; g2++) {
      uint2 pk;
      pk.x = pack_bf16x2(o[mi2][4 * g2 + 0] * inv, o[mi2][4 * g2 + 1] * inv);
      pk.y = pack_bf16x2(o[mi2][4 * g2 + 2] * inv, o[mi2][4 * g2 + 3] * inv);
      *(uint2*)(myP + l32 * 72 + mi2 * 32 + g2 * 8 + h * 4) = pk;
    }
  const int b = bh >> 4, head = bh & 15;
#pragma unroll
  for (int p = 0; p < 4; p++) {
    int r = p * 8 + (lane >> 3);
    int c = (lane & 7) * 8;
    uint4 vv = *(const uint4*)(myP + r * 72 + c);
    *(uint4*)(ctx + ((size_t)(b * S_ + qc * 32 + r)) * DOUT + head * 64 + c) = vv;
  }
}

// ---------- flash attention, causal — S^T form, one chunk/wave, 128-key pairs ----------
// 512 blocks x 8 waves = 4096 waves co-resident (16/CU, 4/SIMD at VGPR<=128).
// Block j carries chunks {63-4j-0..3} U {4j+0..3}: per-block work uniform (~132 tiles),
// so the 2 blocks/CU stay balanced. bh in low 6 bits -> same-bh blocks share an XCD L2.
__global__ __launch_bounds__(512, 4) void attn_kernel(
    const unsigned short* __restrict__ Q,
    const unsigned short* __restrict__ Kmat,
    const unsigned short* __restrict__ Vt,
    unsigned short* __restrict__ ctx) {
  __shared__ __attribute__((aligned(16))) unsigned short PsT[256 * 72];

  const int tid = threadIdx.x;
  const int lane = tid & 63;
  const int w = tid >> 6;
  const int l32 = lane & 31;
  const int h = lane >> 5;

  const int bh = blockIdx.x & 63;
  const int j = blockIdx.x >> 6;                     // 0..7
  const int qc = (w < 4) ? 63 - (j * 4 + w) : (j * 4 + w - 4);
  const int nt = (qc >> 1) + 1;                      // 1..32 tiles of 64 keys

  const unsigned short* Qh = Q + (size_t)bh * S_ * HD;
  const unsigned short* Kh = Kmat + (size_t)bh * S_ * HD;
  const unsigned short* Vh = Vt + (size_t)bh * HD * S_;

  const int qrow = qc * 32 + l32;

  short8 qf[4];
#pragma unroll
  for (int ks = 0; ks < 4; ks++)
    qf[ks] = *(const short8*)(Qh + (size_t)qrow * HD + ks * 16 + h * 8);

  f32x16 oacc[2] = {};
  float m_run = -__builtin_inff(), l_run = 0.f;
  unsigned short* myP = PsT + (size_t)(w * 32) * 72;

  const int nPair = nt >> 1;
  const bool leftover = nt & 1;
  int kt = 0;
  for (int p = 0; p < nPair; p++, kt += 2) {
    const int k0 = kt * 64, k1 = k0 + 64;
    f32x16 s0[2] = {}, s1[2] = {};
#pragma unroll
    for (int ks = 0; ks < 4; ks++)
#pragma unroll
      for (int mi = 0; mi < 2; mi++) {
        short8 kf0 = *(const short8*)(Kh + (size_t)(k0 + mi * 32 + l32) * HD + ks * 16 + h * 8);
        short8 kf1 = *(const short8*)(Kh + (size_t)(k1 + mi * 32 + l32) * HD + ks * 16 + h * 8);
        s0[mi] = __builtin_amdgcn_mfma_f32_32x32x16_bf16(kf0, qf[ks], s0[mi], 0, 0, 0);
        s1[mi] = __builtin_amdgcn_mfma_f32_32x32x16_bf16(kf1, qf[ks], s1[mi], 0, 0, 0);
      }
    short8 vf0[4][2], vf1[4][2];
#pragma unroll
    for (int ks2 = 0; ks2 < 4; ks2++)
#pragma unroll
      for (int mi2 = 0; mi2 < 2; mi2++) {
        vf0[ks2][mi2] = *(const short8*)(Vh + (size_t)(mi2 * 32 + l32) * S_ + k0 + ks2 * 16 + h * 8);
        vf1[ks2][mi2] = *(const short8*)(Vh + (size_t)(mi2 * 32 + l32) * S_ + k1 + ks2 * 16 + h * 8);
      }
    const bool diag1 = (!leftover) && (p == nPair - 1);
    softmax_pair(s0, s1, m_run, l_run, oacc, diag1, qrow, k1, h);
    pv_tile(s0, oacc, vf0, myP, l32, h);
    pv_tile(s1, oacc, vf1, myP, l32, h);
  }
  if (leftover) {
    const int k0 = kt * 64;
    short8 vf[4][2];
#pragma unroll
    for (int ks2 = 0; ks2 < 4; ks2++)
#pragma unroll
      for (int mi2 = 0; mi2 < 2; mi2++)
        vf[ks2][mi2] = *(const short8*)(Vh + (size_t)(mi2 * 32 + l32) * S_ + k0 + ks2 * 16 + h * 8);
    f32x16 sA[2] = {};
#pragma unroll
    for (int ks = 0; ks < 4; ks++)
#pragma unroll
      for (int mi = 0; mi < 2; mi++) {
        short8 kf = *(const short8*)(Kh + (size_t)(k0 + mi * 32 + l32) * HD + ks * 16 + h * 8);
        sA[mi] = __builtin_amdgcn_mfma_f32_32x32x16_bf16(kf, qf[ks], sA[mi], 0, 0, 0);
      }
    softmax_tile(sA, m_run, l_run, oacc, true, qrow, k0, h);
    pv_tile(sA, oacc, vf, myP, l32, h);
  }

  store_chunk(oacc, l_run, qc, myP, ctx, bh, lane, l32, h);
}

extern "C" void kernel_launch(void* const* d_in, const int* in_sizes, int n_in,
                              void* d_out, int out_size, void* d_ws, size_t ws_size,
                              hipStream_t stream) {
  const float* x  = (const float*)d_in[0];
  const float* Wq = (const float*)d_in[1];
  const float* Wk = (const float*)d_in[2];
  const float* Wv = (const float*)d_in[3];
  const float* Wo = (const float*)d_in[4];
  const float* bo = (const float*)d_in[5];
  float* out = (float*)d_out;
  char* ws = (char*)d_ws;

  const size_t MB = 1024 * 1024;
  unsigned short* Wqt = (unsigned short*)(ws + 0 * MB);   // contiguous 6 MB: QKV weights
  unsigned short* Wkt = (unsigned short*)(ws + 2 * MB);
  unsigned short* Wvt = (unsigned short*)(ws + 4 * MB);
  unsigned short* Wot = (unsigned short*)(ws + 6 * MB);
  unsigned short* xb  = (unsigned short*)(ws + 8 * MB);
  unsigned short* Qb  = (unsigned short*)(ws + 24 * MB);
  unsigned short* Kb  = (unsigned short*)(ws + 40 * MB);
  unsigned short* Vb  = (unsigned short*)(ws + 56 * MB);
  unsigned short* Vtb = (unsigned short*)(ws + 72 * MB);
  unsigned short* ctxb = xb;   // xb dead after QKV GEMM

  cvt_kernel<<<8192, 256, 0, stream>>>(x, xb, 2097152);
  wtrans_kernel<<<dim3(16, 16), 256, 0, stream>>>(Wq, Wqt);
  wtrans_kernel<<<dim3(16, 16), 256, 0, stream>>>(Wk, Wkt);
  wtrans_kernel<<<dim3(16, 16), 256, 0, stream>>>(Wv, Wvt);
  wtrans_kernel<<<dim3(16, 16), 256, 0, stream>>>(Wo, Wot);
  gemm_kernel<0><<<dim3(64, 24), 256, 0, stream>>>(xb, Wqt, Qb, Kb, Vb, nullptr, nullptr,
                                                   8192, 3072, 1024);
  vtrans_kernel<<<dim3(32, 64), 256, 0, stream>>>(Vb, Vtb);
  attn_kernel<<<512, 512, 0, stream>>>(Qb, Kb, Vtb, ctxb);
  gemm_kernel<1><<<dim3(64, 8), 256, 0, stream>>>(ctxb, Wot, nullptr, nullptr, nullptr, out, bo,
                                                  8192, 1024, 1024);
}

// Round 7
// 333.948 us; speedup vs baseline: 1.8257x; 1.8257x over previous
//
#include <hip/hip_runtime.h>
#include <stdint.h>

#define B_   4
#define S_   2048
#define DI   1024
#define DOUT 1024
#define NHD  16
#define HD   64

typedef __attribute__((ext_vector_type(8))) short short8;
typedef __attribute__((ext_vector_type(4))) float f32x4;
typedef __attribute__((ext_vector_type(16))) float f32x16;

__device__ __forceinline__ unsigned short f32_bf16(float f) {
  union { float f; unsigned u; } v; v.f = f;
  unsigned r = v.u + 0x7FFFu + ((v.u >> 16) & 1u);   // RNE
  return (unsigned short)(r >> 16);
}

__device__ __forceinline__ unsigned pack_bf16x2(float a, float b) {
  union { float f; unsigned u; } x, y; x.f = a; y.f = b;
  return ((y.u + 0x8000u) & 0xFFFF0000u) | ((x.u + 0x8000u) >> 16);
}

// async 16B global->LDS (dst wave-uniform; HW adds lane*16)
__device__ __forceinline__ void gl_lds16(const void* g, void* s) {
  __builtin_amdgcn_global_load_lds(
      (const __attribute__((address_space(1))) unsigned int*)g,
      (__attribute__((address_space(3))) unsigned int*)s, 16, 0, 0);
}

#define EXP2(x) __builtin_amdgcn_exp2f(x)

// ---------- elementwise fp32 -> bf16 ----------
__global__ __launch_bounds__(256) void cvt_kernel(const float* __restrict__ src,
                                                  unsigned short* __restrict__ dst, int n4) {
  int i = blockIdx.x * blockDim.x + threadIdx.x;
  if (i < n4) {
    float4 v = ((const float4*)src)[i];
    ushort4 o;
    o.x = f32_bf16(v.x); o.y = f32_bf16(v.y); o.z = f32_bf16(v.z); o.w = f32_bf16(v.w);
    ((ushort4*)dst)[i] = o;
  }
}

// ---------- weight transpose+convert: W[k][n] f32 -> Wt[n][k] bf16 ----------
__global__ __launch_bounds__(256) void wtrans_kernel(const float* __restrict__ W,
                                                     unsigned short* __restrict__ Wt) {
  __shared__ __attribute__((aligned(16))) float tile[64][65];
  const int k0 = blockIdx.y * 64;
  const int n0 = blockIdx.x * 64;
  const int tid = threadIdx.x;
#pragma unroll
  for (int i = 0; i < 4; i++) {
    int c = tid + i * 256;
    int r = c >> 4;
    int cc = (c & 15) * 4;
    float4 v = *(const float4*)(W + (size_t)(k0 + r) * DOUT + n0 + cc);
    tile[r][cc] = v.x; tile[r][cc + 1] = v.y; tile[r][cc + 2] = v.z; tile[r][cc + 3] = v.w;
  }
  __syncthreads();
#pragma unroll
  for (int i = 0; i < 4; i++) {
    int c = tid + i * 256;
    int r = c >> 4;
    int cc = (c & 15) * 4;
    ushort4 o;
    o.x = f32_bf16(tile[cc + 0][r]);
    o.y = f32_bf16(tile[cc + 1][r]);
    o.z = f32_bf16(tile[cc + 2][r]);
    o.w = f32_bf16(tile[cc + 3][r]);
    *(ushort4*)(Wt + (size_t)(n0 + r) * DI + k0 + cc) = o;
  }
}

// ---------- V transpose: Vb[bh][s][hd] -> Vt[bh][hd][s] (bf16) ----------
__global__ __launch_bounds__(256) void vtrans_kernel(const unsigned short* __restrict__ Vb,
                                                     unsigned short* __restrict__ Vt) {
  __shared__ __attribute__((aligned(16))) unsigned short tile[64][72];
  const int bh = blockIdx.y;
  const int s0 = blockIdx.x * 64;
  const int tid = threadIdx.x;
  const unsigned short* src = Vb + (size_t)bh * S_ * HD + (size_t)s0 * HD;
#pragma unroll
  for (int i = 0; i < 2; i++) {
    int c = tid + i * 256;
    int r = c >> 3;
    int cc = (c & 7) * 8;
    *(uint4*)(&tile[r][cc]) = *(const uint4*)(src + r * HD + cc);
  }
  __syncthreads();
  unsigned short* dst = Vt + (size_t)bh * HD * S_ + s0;
#pragma unroll
  for (int i = 0; i < 2; i++) {
    int c = tid + i * 256;
    int r = c >> 3;
    int cc = (c & 7) * 8;
    union { unsigned short u[8]; uint4 v; } t;
#pragma unroll
    for (int j = 0; j < 8; j++) t.u[j] = tile[cc + j][r];
    *(uint4*)(dst + (size_t)r * S_ + cc) = t.v;
  }
}

// ---------- GEMM (m97 recipe). MODE 0: fused QKV (N=3072) scatter to head-major.
// MODE 1: fp32 row-major + bias. ----------
template <int MODE>
__global__ __launch_bounds__(256) void gemm_kernel(
    const unsigned short* __restrict__ A,
    const unsigned short* __restrict__ Bt,
    unsigned short* __restrict__ oQ,
    unsigned short* __restrict__ oK,
    unsigned short* __restrict__ oV,
    float* __restrict__ outF,
    const float* __restrict__ bias,
    int M, int N, int K) {
  __shared__ __attribute__((aligned(16))) unsigned short Asm_[128 * 32];
  __shared__ __attribute__((aligned(16))) unsigned short Bsm_[128 * 32];
  const int tid = threadIdx.x;
  const int lane = tid & 63;
  const int w = tid >> 6;
  const int wm = w >> 1, wn = w & 1;
  const int quad = lane >> 4, l16 = lane & 15;
  const int m0 = blockIdx.x * 128;
  const int n0 = blockIdx.y * 128;

  const int lr = lane >> 2;
  const int lc8 = (lane & 3) * 8;
  const unsigned short* gA0 = A + (size_t)(m0 + w * 32 + lr) * K + lc8;
  const unsigned short* gA1 = gA0 + (size_t)16 * K;
  const unsigned short* gB0 = Bt + (size_t)(n0 + w * 32 + lr) * K + lc8;
  const unsigned short* gB1 = gB0 + (size_t)16 * K;
  unsigned short* sA0 = Asm_ + (w * 2 + 0) * 512;
  unsigned short* sA1 = Asm_ + (w * 2 + 1) * 512;
  unsigned short* sB0 = Bsm_ + (w * 2 + 0) * 512;
  unsigned short* sB1 = Bsm_ + (w * 2 + 1) * 512;

  f32x4 acc[4][4] = {};

  for (int k0 = 0; k0 < K; k0 += 32) {
    __syncthreads();
    gl_lds16(gA0 + k0, sA0);
    gl_lds16(gA1 + k0, sA1);
    gl_lds16(gB0 + k0, sB0);
    gl_lds16(gB1 + k0, sB1);
    __syncthreads();
    short8 af[4], bfr[4];
#pragma unroll
    for (int mi = 0; mi < 4; mi++)
      af[mi] = *(const short8*)(Asm_ + (wm * 64 + mi * 16 + l16) * 32 + quad * 8);
#pragma unroll
    for (int ni = 0; ni < 4; ni++)
      bfr[ni] = *(const short8*)(Bsm_ + (wn * 64 + ni * 16 + l16) * 32 + quad * 8);
#pragma unroll
    for (int mi = 0; mi < 4; mi++)
#pragma unroll
      for (int ni = 0; ni < 4; ni++)
        acc[mi][ni] = __builtin_amdgcn_mfma_f32_16x16x32_bf16(af[mi], bfr[ni], acc[mi][ni], 0, 0, 0);
  }

  unsigned short* dst0 = nullptr;
  if (MODE == 0) {
    const int which = n0 >> 10;                 // block-uniform: 0=Q,1=K,2=V
    dst0 = which == 0 ? oQ : which == 1 ? oK : oV;
  }
#pragma unroll
  for (int mi = 0; mi < 4; mi++) {
#pragma unroll
    for (int ni = 0; ni < 4; ni++) {
      const int col = n0 + wn * 64 + ni * 16 + l16;
      float bv = (MODE == 1) ? bias[col] : 0.f;
#pragma unroll
      for (int r = 0; r < 4; r++) {
        const int row = m0 + wm * 64 + mi * 16 + quad * 4 + r;
        if (MODE == 0) {
          int b = row >> 11, s = row & 2047;
          int h = (col >> 6) & 15, hd = col & 63;
          dst0[(((size_t)(b * NHD + h)) * S_ + s) * HD + hd] = f32_bf16(acc[mi][ni][r]);
        } else {
          outF[(size_t)row * N + col] = acc[mi][ni][r] + bv;
        }
      }
    }
  }
}

// ---------- flash attention, causal — S^T form, single chunk/wave (R3 body),
// balanced block composition (R6 map), 512 blocks = 2/CU co-resident. ----------
// VGPR target ~68 (R3 codegen) -> 4 waves/SIMD possible; LDS 36.9 KB -> 4 blocks OK.
__global__ __launch_bounds__(512, 2) void attn_kernel(
    const unsigned short* __restrict__ Q,
    const unsigned short* __restrict__ Kmat,
    const unsigned short* __restrict__ Vt,
    unsigned short* __restrict__ ctx) {
  __shared__ __attribute__((aligned(16))) unsigned short PsT[256 * 72];

  const int tid = threadIdx.x;
  const int lane = tid & 63;
  const int w = tid >> 6;          // 0..7
  const int l32 = lane & 31;
  const int h = lane >> 5;

  const int bh = blockIdx.x & 63;              // same-bh blocks share an XCD L2
  const int j = blockIdx.x >> 6;               // 0..7
  // balanced composition: waves 0-3 heavy chunks, waves 4-7 complementary light ones
  const int qc = (w < 4) ? 63 - (j * 4 + w) : (j * 4 + (w - 4));
  const int nt = (qc >> 1) + 1;

  const unsigned short* Qh = Q + (size_t)bh * S_ * HD;
  const unsigned short* Kh = Kmat + (size_t)bh * S_ * HD;
  const unsigned short* Vh = Vt + (size_t)bh * HD * S_;

  const int qrow = qc * 32 + l32;

  short8 qf[4];
#pragma unroll
  for (int ks = 0; ks < 4; ks++)
    qf[ks] = *(const short8*)(Qh + (size_t)qrow * HD + ks * 16 + h * 8);

  f32x16 oacc[2] = {};
  float m_run = -__builtin_inff();
  float l_run = 0.f;

  unsigned short* myP = PsT + (size_t)(w * 32) * 72;
  const float scl = 0.18033688f;   // (1/sqrt(64)) * log2(e)

  for (int kt = 0; kt < nt; kt++) {
    const int k0 = kt * 64;

    // ---- V prefetch (independent; hides under S-MFMA + softmax) ----
    short8 vf[4][2];
#pragma unroll
    for (int ks2 = 0; ks2 < 4; ks2++)
#pragma unroll
      for (int mi2 = 0; mi2 < 2; mi2++)
        vf[ks2][mi2] = *(const short8*)(Vh + (size_t)(mi2 * 32 + l32) * S_ + k0 + ks2 * 16 + h * 8);

    // ---- S^T = K * Q^T ----
    f32x16 sacc[2] = {};
#pragma unroll
    for (int ks = 0; ks < 4; ks++)
#pragma unroll
      for (int mi = 0; mi < 2; mi++) {
        short8 kf = *(const short8*)(Kh + (size_t)(k0 + mi * 32 + l32) * HD + ks * 16 + h * 8);
        sacc[mi] = __builtin_amdgcn_mfma_f32_32x32x16_bf16(kf, qf[ks], sacc[mi], 0, 0, 0);
      }

    // ---- online softmax (log2 domain) ----
    if (kt == nt - 1) {   // diagonal tile: mask
#pragma unroll
      for (int mi = 0; mi < 2; mi++)
#pragma unroll
        for (int e = 0; e < 16; e++) {
          int key = k0 + mi * 32 + (e & 3) + 8 * (e >> 2) + 4 * h;
          if (key > qrow) sacc[mi][e] = -__builtin_inff();
        }
    }
    float vmax = -__builtin_inff();
#pragma unroll
    for (int mi = 0; mi < 2; mi++)
#pragma unroll
      for (int e = 0; e < 16; e++) vmax = fmaxf(vmax, sacc[mi][e]);
    vmax = fmaxf(vmax, __shfl_xor(vmax, 32));
    const float mnew = fmaxf(m_run, vmax * scl);
    const float alpha = EXP2(m_run - mnew);
    m_run = mnew;

    float rs = 0.f;
#pragma unroll
    for (int mi = 0; mi < 2; mi++)
#pragma unroll
      for (int e = 0; e < 16; e++) {
        float p = EXP2(fmaf(sacc[mi][e], scl, -mnew));
        sacc[mi][e] = p;
        rs += p;
      }
    rs += __shfl_xor(rs, 32);
    l_run = l_run * alpha + rs;
#pragma unroll
    for (int mi = 0; mi < 2; mi++) oacc[mi] *= alpha;

    // ---- P -> LDS PsT[qrow][key] packed b64 ----
#pragma unroll
    for (int mi = 0; mi < 2; mi++)
#pragma unroll
      for (int g = 0; g < 4; g++) {
        uint2 pk;
        pk.x = pack_bf16x2(sacc[mi][4 * g + 0], sacc[mi][4 * g + 1]);
        pk.y = pack_bf16x2(sacc[mi][4 * g + 2], sacc[mi][4 * g + 3]);
        *(uint2*)(myP + l32 * 72 + mi * 32 + g * 8 + h * 4) = pk;
      }

    // ---- O^T += V^T * P^T ----
#pragma unroll
    for (int ks2 = 0; ks2 < 4; ks2++) {
      short8 pf = *(const short8*)(myP + l32 * 72 + ks2 * 16 + h * 8);
#pragma unroll
      for (int mi2 = 0; mi2 < 2; mi2++)
        oacc[mi2] = __builtin_amdgcn_mfma_f32_32x32x16_bf16(vf[ks2][mi2], pf, oacc[mi2], 0, 0, 0);
    }
  }

  // ---- epilogue: O^T / l -> LDS (reuse myP) -> coalesced 16B stores ----
  const float inv = 1.f / l_run;
#pragma unroll
  for (int mi2 = 0; mi2 < 2; mi2++)
#pragma unroll
    for (int g = 0; g < 4; g++) {
      uint2 pk;
      pk.x = pack_bf16x2(oacc[mi2][4 * g + 0] * inv, oacc[mi2][4 * g + 1] * inv);
      pk.y = pack_bf16x2(oacc[mi2][4 * g + 2] * inv, oacc[mi2][4 * g + 3] * inv);
      *(uint2*)(myP + l32 * 72 + mi2 * 32 + g * 8 + h * 4) = pk;
    }
  const int b = bh >> 4, head = bh & 15;
#pragma unroll
  for (int p = 0; p < 4; p++) {
    int r = p * 8 + (lane >> 3);
    int c = (lane & 7) * 8;
    uint4 vv = *(const uint4*)(myP + r * 72 + c);
    *(uint4*)(ctx + ((size_t)(b * S_ + qc * 32 + r)) * DOUT + head * 64 + c) = vv;
  }
}

extern "C" void kernel_launch(void* const* d_in, const int* in_sizes, int n_in,
                              void* d_out, int out_size, void* d_ws, size_t ws_size,
                              hipStream_t stream) {
  const float* x  = (const float*)d_in[0];
  const float* Wq = (const float*)d_in[1];
  const float* Wk = (const float*)d_in[2];
  const float* Wv = (const float*)d_in[3];
  const float* Wo = (const float*)d_in[4];
  const float* bo = (const float*)d_in[5];
  float* out = (float*)d_out;
  char* ws = (char*)d_ws;

  const size_t MB = 1024 * 1024;
  unsigned short* Wqt = (unsigned short*)(ws + 0 * MB);   // contiguous 6 MB: QKV weights
  unsigned short* Wkt = (unsigned short*)(ws + 2 * MB);
  unsigned short* Wvt = (unsigned short*)(ws + 4 * MB);
  unsigned short* Wot = (unsigned short*)(ws + 6 * MB);
  unsigned short* xb  = (unsigned short*)(ws + 8 * MB);
  unsigned short* Qb  = (unsigned short*)(ws + 24 * MB);
  unsigned short* Kb  = (unsigned short*)(ws + 40 * MB);
  unsigned short* Vb  = (unsigned short*)(ws + 56 * MB);
  unsigned short* Vtb = (unsigned short*)(ws + 72 * MB);
  unsigned short* ctxb = xb;   // xb dead after QKV GEMM

  cvt_kernel<<<8192, 256, 0, stream>>>(x, xb, 2097152);
  wtrans_kernel<<<dim3(16, 16), 256, 0, stream>>>(Wq, Wqt);
  wtrans_kernel<<<dim3(16, 16), 256, 0, stream>>>(Wk, Wkt);
  wtrans_kernel<<<dim3(16, 16), 256, 0, stream>>>(Wv, Wvt);
  wtrans_kernel<<<dim3(16, 16), 256, 0, stream>>>(Wo, Wot);
  gemm_kernel<0><<<dim3(64, 24), 256, 0, stream>>>(xb, Wqt, Qb, Kb, Vb, nullptr, nullptr,
                                                   8192, 3072, 1024);
  vtrans_kernel<<<dim3(32, 64), 256, 0, stream>>>(Vb, Vtb);
  attn_kernel<<<512, 512, 0, stream>>>(Qb, Kb, Vtb, ctxb);
  gemm_kernel<1><<<dim3(64, 8), 256, 0, stream>>>(ctxb, Wot, nullptr, nullptr, nullptr, out, bo,
                                                  8192, 1024, 1024);
}

// Round 8
// 283.967 us; speedup vs baseline: 2.1471x; 1.1760x over previous
//
#include <hip/hip_runtime.h>
#include <stdint.h>

#define B_   4
#define S_   2048
#define DI   1024
#define DOUT 1024
#define NHD  16
#define HD   64

typedef __attribute__((ext_vector_type(8))) short short8;
typedef __attribute__((ext_vector_type(4))) float f32x4;
typedef __attribute__((ext_vector_type(16))) float f32x16;

__device__ __forceinline__ unsigned short f32_bf16(float f) {
  union { float f; unsigned u; } v; v.f = f;
  unsigned r = v.u + 0x7FFFu + ((v.u >> 16) & 1u);   // RNE
  return (unsigned short)(r >> 16);
}

__device__ __forceinline__ unsigned pack_bf16x2(float a, float b) {
  union { float f; unsigned u; } x, y; x.f = a; y.f = b;
  return ((y.u + 0x8000u) & 0xFFFF0000u) | ((x.u + 0x8000u) >> 16);
}

// async 16B global->LDS (dst wave-uniform; HW adds lane*16)
__device__ __forceinline__ void gl_lds16(const void* g, void* s) {
  __builtin_amdgcn_global_load_lds(
      (const __attribute__((address_space(1))) unsigned int*)g,
      (__attribute__((address_space(3))) unsigned int*)s, 16, 0, 0);
}

#define EXP2(x) __builtin_amdgcn_exp2f(x)

// ---------- elementwise fp32 -> bf16 ----------
__global__ __launch_bounds__(256) void cvt_kernel(const float* __restrict__ src,
                                                  unsigned short* __restrict__ dst, int n4) {
  int i = blockIdx.x * blockDim.x + threadIdx.x;
  if (i < n4) {
    float4 v = ((const float4*)src)[i];
    ushort4 o;
    o.x = f32_bf16(v.x); o.y = f32_bf16(v.y); o.z = f32_bf16(v.z); o.w = f32_bf16(v.w);
    ((ushort4*)dst)[i] = o;
  }
}

// ---------- weight transpose+convert: W[k][n] f32 -> Wt[n][k] bf16 ----------
__global__ __launch_bounds__(256) void wtrans_kernel(const float* __restrict__ W,
                                                     unsigned short* __restrict__ Wt) {
  __shared__ __attribute__((aligned(16))) float tile[64][65];
  const int k0 = blockIdx.y * 64;
  const int n0 = blockIdx.x * 64;
  const int tid = threadIdx.x;
#pragma unroll
  for (int i = 0; i < 4; i++) {
    int c = tid + i * 256;
    int r = c >> 4;
    int cc = (c & 15) * 4;
    float4 v = *(const float4*)(W + (size_t)(k0 + r) * DOUT + n0 + cc);
    tile[r][cc] = v.x; tile[r][cc + 1] = v.y; tile[r][cc + 2] = v.z; tile[r][cc + 3] = v.w;
  }
  __syncthreads();
#pragma unroll
  for (int i = 0; i < 4; i++) {
    int c = tid + i * 256;
    int r = c >> 4;
    int cc = (c & 15) * 4;
    ushort4 o;
    o.x = f32_bf16(tile[cc + 0][r]);
    o.y = f32_bf16(tile[cc + 1][r]);
    o.z = f32_bf16(tile[cc + 2][r]);
    o.w = f32_bf16(tile[cc + 3][r]);
    *(ushort4*)(Wt + (size_t)(n0 + r) * DI + k0 + cc) = o;
  }
}

// ---------- V transpose: Vb[bh][s][hd] -> Vt[bh][hd][s] (bf16) ----------
__global__ __launch_bounds__(256) void vtrans_kernel(const unsigned short* __restrict__ Vb,
                                                     unsigned short* __restrict__ Vt) {
  __shared__ __attribute__((aligned(16))) unsigned short tile[64][72];
  const int bh = blockIdx.y;
  const int s0 = blockIdx.x * 64;
  const int tid = threadIdx.x;
  const unsigned short* src = Vb + (size_t)bh * S_ * HD + (size_t)s0 * HD;
#pragma unroll
  for (int i = 0; i < 2; i++) {
    int c = tid + i * 256;
    int r = c >> 3;
    int cc = (c & 7) * 8;
    *(uint4*)(&tile[r][cc]) = *(const uint4*)(src + r * HD + cc);
  }
  __syncthreads();
  unsigned short* dst = Vt + (size_t)bh * HD * S_ + s0;
#pragma unroll
  for (int i = 0; i < 2; i++) {
    int c = tid + i * 256;
    int r = c >> 3;
    int cc = (c & 7) * 8;
    union { unsigned short u[8]; uint4 v; } t;
#pragma unroll
    for (int j = 0; j < 8; j++) t.u[j] = tile[cc + j][r];
    *(uint4*)(dst + (size_t)r * S_ + cc) = t.v;
  }
}

// ---------- GEMM (m97 recipe). MODE 0: fused QKV (N=3072) scatter to head-major.
// MODE 1: fp32 row-major + bias. ----------
template <int MODE>
__global__ __launch_bounds__(256) void gemm_kernel(
    const unsigned short* __restrict__ A,
    const unsigned short* __restrict__ Bt,
    unsigned short* __restrict__ oQ,
    unsigned short* __restrict__ oK,
    unsigned short* __restrict__ oV,
    float* __restrict__ outF,
    const float* __restrict__ bias,
    int M, int N, int K) {
  __shared__ __attribute__((aligned(16))) unsigned short Asm_[128 * 32];
  __shared__ __attribute__((aligned(16))) unsigned short Bsm_[128 * 32];
  const int tid = threadIdx.x;
  const int lane = tid & 63;
  const int w = tid >> 6;
  const int wm = w >> 1, wn = w & 1;
  const int quad = lane >> 4, l16 = lane & 15;
  const int m0 = blockIdx.x * 128;
  const int n0 = blockIdx.y * 128;

  const int lr = lane >> 2;
  const int lc8 = (lane & 3) * 8;
  const unsigned short* gA0 = A + (size_t)(m0 + w * 32 + lr) * K + lc8;
  const unsigned short* gA1 = gA0 + (size_t)16 * K;
  const unsigned short* gB0 = Bt + (size_t)(n0 + w * 32 + lr) * K + lc8;
  const unsigned short* gB1 = gB0 + (size_t)16 * K;
  unsigned short* sA0 = Asm_ + (w * 2 + 0) * 512;
  unsigned short* sA1 = Asm_ + (w * 2 + 1) * 512;
  unsigned short* sB0 = Bsm_ + (w * 2 + 0) * 512;
  unsigned short* sB1 = Bsm_ + (w * 2 + 1) * 512;

  f32x4 acc[4][4] = {};

  for (int k0 = 0; k0 < K; k0 += 32) {
    __syncthreads();
    gl_lds16(gA0 + k0, sA0);
    gl_lds16(gA1 + k0, sA1);
    gl_lds16(gB0 + k0, sB0);
    gl_lds16(gB1 + k0, sB1);
    __syncthreads();
    short8 af[4], bfr[4];
#pragma unroll
    for (int mi = 0; mi < 4; mi++)
      af[mi] = *(const short8*)(Asm_ + (wm * 64 + mi * 16 + l16) * 32 + quad * 8);
#pragma unroll
    for (int ni = 0; ni < 4; ni++)
      bfr[ni] = *(const short8*)(Bsm_ + (wn * 64 + ni * 16 + l16) * 32 + quad * 8);
#pragma unroll
    for (int mi = 0; mi < 4; mi++)
#pragma unroll
      for (int ni = 0; ni < 4; ni++)
        acc[mi][ni] = __builtin_amdgcn_mfma_f32_16x16x32_bf16(af[mi], bfr[ni], acc[mi][ni], 0, 0, 0);
  }

  unsigned short* dst0 = nullptr;
  if (MODE == 0) {
    const int which = n0 >> 10;                 // block-uniform: 0=Q,1=K,2=V
    dst0 = which == 0 ? oQ : which == 1 ? oK : oV;
  }
#pragma unroll
  for (int mi = 0; mi < 4; mi++) {
#pragma unroll
    for (int ni = 0; ni < 4; ni++) {
      const int col = n0 + wn * 64 + ni * 16 + l16;
      float bv = (MODE == 1) ? bias[col] : 0.f;
#pragma unroll
      for (int r = 0; r < 4; r++) {
        const int row = m0 + wm * 64 + mi * 16 + quad * 4 + r;
        if (MODE == 0) {
          int b = row >> 11, s = row & 2047;
          int h = (col >> 6) & 15, hd = col & 63;
          dst0[(((size_t)(b * NHD + h)) * S_ + s) * HD + hd] = f32_bf16(acc[mi][ni][r]);
        } else {
          outF[(size_t)row * N + col] = acc[mi][ni][r] + bv;
        }
      }
    }
  }
}

// ---------- flash attention, causal — block-cooperative LDS-staged K/V ----------
// 8 waves/block share one bh; K & V tiles staged ONCE per block into
// double-buffered, XOR-swizzled LDS (coalesced global reads: ~16 lines/wave vs
// ~768 TA-cyc/tile/wave for row-per-lane global fragments). One barrier/tile.
// j-map {7,6,5,4,0,1,2,3}: blocks c and c+256 sum to 36 tiles -> CU-balanced.
__global__ __launch_bounds__(512, 2) void attn_kernel(
    const unsigned short* __restrict__ Q,
    const unsigned short* __restrict__ Kmat,
    const unsigned short* __restrict__ Vt,
    unsigned short* __restrict__ ctx) {
  __shared__ __attribute__((aligned(16))) unsigned short Ks[2][64 * 64];  // 8 KB each
  __shared__ __attribute__((aligned(16))) unsigned short Vs[2][64 * 64];
  __shared__ __attribute__((aligned(16))) unsigned short PsT[256 * 72];   // 36 KB

  const int tid = threadIdx.x;
  const int lane = tid & 63;
  const int w = tid >> 6;          // 0..7
  const int l32 = lane & 31;
  const int h = lane >> 5;

  const int bh = blockIdx.x & 63;
  const int i4 = blockIdx.x >> 6;                    // 0..7
  const int jj = (i4 < 4) ? 7 - i4 : i4 - 4;         // pairs (c,c+256) sum to 7
  const int qc = jj * 8 + w;
  const int nt = (qc >> 1) + 1;                      // this wave's tile count
  const int ntmax = jj * 4 + 4;                      // block's tile count (= nt of w=7)

  const unsigned short* Qh = Q + (size_t)bh * S_ * HD;
  const unsigned short* Kh = Kmat + (size_t)bh * S_ * HD;
  const unsigned short* Vh = Vt + (size_t)bh * HD * S_;

  const int qrow = qc * 32 + l32;

  short8 qf[4];
#pragma unroll
  for (int ks = 0; ks < 4; ks++)
    qf[ks] = *(const short8*)(Qh + (size_t)qrow * HD + ks * 16 + h * 8);

  // staging map: thread -> (row sr, 16B chunk sj), XOR-swizzled LDS chunk
  const int sr = tid >> 3;                 // 0..63
  const int sj = tid & 7;                  // 0..7
  const int ssw = sr * 64 + ((sj ^ (sr & 7)) << 3);
  const unsigned short* gK = Kh + (size_t)sr * HD + sj * 8;   // + kt*64*HD
  const unsigned short* gV = Vh + (size_t)sr * S_ + sj * 8;   // + kt*64
  const int swz = (l32 & 7);               // fragment-read swizzle key

  // stage tile 0
  uint4 kreg = *(const uint4*)(gK);
  uint4 vreg = *(const uint4*)(gV);
  *(uint4*)(&Ks[0][ssw]) = kreg;
  *(uint4*)(&Vs[0][ssw]) = vreg;
  __syncthreads();

  f32x16 oacc[2] = {};
  float m_run = -__builtin_inff();
  float l_run = 0.f;
  unsigned short* myP = PsT + (size_t)(w * 32) * 72;
  const float scl = 0.18033688f;   // (1/sqrt(64)) * log2(e)

  for (int kt = 0; kt < ntmax; kt++) {
    // prefetch next tile into regs (lands during compute)
    if (kt + 1 < ntmax) {
      kreg = *(const uint4*)(gK + (size_t)(kt + 1) * 64 * HD);
      vreg = *(const uint4*)(gV + (size_t)(kt + 1) * 64);
    }
    const unsigned short* Kb_ = Ks[kt & 1];
    const unsigned short* Vb_ = Vs[kt & 1];

    if (kt < nt) {
      const int k0 = kt * 64;
      // ---- S^T = K * Q^T (fragments from swizzled LDS) ----
      f32x16 sacc[2] = {};
#pragma unroll
      for (int ks = 0; ks < 4; ks++)
#pragma unroll
        for (int mi = 0; mi < 2; mi++) {
          short8 kf = *(const short8*)(Kb_ + (mi * 32 + l32) * 64 + (((ks * 2 + h) ^ swz) << 3));
          sacc[mi] = __builtin_amdgcn_mfma_f32_32x32x16_bf16(kf, qf[ks], sacc[mi], 0, 0, 0);
        }

      // ---- online softmax ----
      if (kt == nt - 1) {
#pragma unroll
        for (int mi = 0; mi < 2; mi++)
#pragma unroll
          for (int e = 0; e < 16; e++) {
            int key = k0 + mi * 32 + (e & 3) + 8 * (e >> 2) + 4 * h;
            if (key > qrow) sacc[mi][e] = -__builtin_inff();
          }
      }
      float vmax = -__builtin_inff();
#pragma unroll
      for (int mi = 0; mi < 2; mi++)
#pragma unroll
        for (int e = 0; e < 16; e++) vmax = fmaxf(vmax, sacc[mi][e]);
      vmax = fmaxf(vmax, __shfl_xor(vmax, 32));
      const float mnew = fmaxf(m_run, vmax * scl);
      const float alpha = EXP2(m_run - mnew);
      m_run = mnew;

      float rs = 0.f;
#pragma unroll
      for (int mi = 0; mi < 2; mi++)
#pragma unroll
        for (int e = 0; e < 16; e++) {
          float p = EXP2(fmaf(sacc[mi][e], scl, -mnew));
          sacc[mi][e] = p;
          rs += p;
        }
      rs += __shfl_xor(rs, 32);
      l_run = l_run * alpha + rs;
#pragma unroll
      for (int mi = 0; mi < 2; mi++) oacc[mi] *= alpha;

      // ---- P -> LDS (wave-private) ----
#pragma unroll
      for (int mi = 0; mi < 2; mi++)
#pragma unroll
        for (int g = 0; g < 4; g++) {
          uint2 pk;
          pk.x = pack_bf16x2(sacc[mi][4 * g + 0], sacc[mi][4 * g + 1]);
          pk.y = pack_bf16x2(sacc[mi][4 * g + 2], sacc[mi][4 * g + 3]);
          *(uint2*)(myP + l32 * 72 + mi * 32 + g * 8 + h * 4) = pk;
        }

      // ---- O^T += V^T * P^T (V fragments from swizzled LDS) ----
#pragma unroll
      for (int ks2 = 0; ks2 < 4; ks2++) {
        short8 pf = *(const short8*)(myP + l32 * 72 + ks2 * 16 + h * 8);
#pragma unroll
        for (int mi2 = 0; mi2 < 2; mi2++) {
          short8 vf = *(const short8*)(Vb_ + (mi2 * 32 + l32) * 64 + (((ks2 * 2 + h) ^ swz) << 3));
          oacc[mi2] = __builtin_amdgcn_mfma_f32_32x32x16_bf16(vf, pf, oacc[mi2], 0, 0, 0);
        }
      }
    }

    // write next tile into the other buffer (safe: its readers passed the
    // previous barrier), then one barrier makes it visible for iter kt+1
    if (kt + 1 < ntmax) {
      *(uint4*)(&Ks[(kt + 1) & 1][ssw]) = kreg;
      *(uint4*)(&Vs[(kt + 1) & 1][ssw]) = vreg;
    }
    __syncthreads();
  }

  // ---- epilogue: O^T / l -> LDS (wave-private) -> coalesced 16B stores ----
  const float inv = 1.f / l_run;
#pragma unroll
  for (int mi2 = 0; mi2 < 2; mi2++)
#pragma unroll
    for (int g = 0; g < 4; g++) {
      uint2 pk;
      pk.x = pack_bf16x2(oacc[mi2][4 * g + 0] * inv, oacc[mi2][4 * g + 1] * inv);
      pk.y = pack_bf16x2(oacc[mi2][4 * g + 2] * inv, oacc[mi2][4 * g + 3] * inv);
      *(uint2*)(myP + l32 * 72 + mi2 * 32 + g * 8 + h * 4) = pk;
    }
  const int b = bh >> 4, head = bh & 15;
#pragma unroll
  for (int p = 0; p < 4; p++) {
    int r = p * 8 + (lane >> 3);
    int c = (lane & 7) * 8;
    uint4 vv = *(const uint4*)(myP + r * 72 + c);
    *(uint4*)(ctx + ((size_t)(b * S_ + qc * 32 + r)) * DOUT + head * 64 + c) = vv;
  }
}

extern "C" void kernel_launch(void* const* d_in, const int* in_sizes, int n_in,
                              void* d_out, int out_size, void* d_ws, size_t ws_size,
                              hipStream_t stream) {
  const float* x  = (const float*)d_in[0];
  const float* Wq = (const float*)d_in[1];
  const float* Wk = (const float*)d_in[2];
  const float* Wv = (const float*)d_in[3];
  const float* Wo = (const float*)d_in[4];
  const float* bo = (const float*)d_in[5];
  float* out = (float*)d_out;
  char* ws = (char*)d_ws;

  const size_t MB = 1024 * 1024;
  unsigned short* Wqt = (unsigned short*)(ws + 0 * MB);   // contiguous 6 MB: QKV weights
  unsigned short* Wkt = (unsigned short*)(ws + 2 * MB);
  unsigned short* Wvt = (unsigned short*)(ws + 4 * MB);
  unsigned short* Wot = (unsigned short*)(ws + 6 * MB);
  unsigned short* xb  = (unsigned short*)(ws + 8 * MB);
  unsigned short* Qb  = (unsigned short*)(ws + 24 * MB);
  unsigned short* Kb  = (unsigned short*)(ws + 40 * MB);
  unsigned short* Vb  = (unsigned short*)(ws + 56 * MB);
  unsigned short* Vtb = (unsigned short*)(ws + 72 * MB);
  unsigned short* ctxb = xb;   // xb dead after QKV GEMM

  cvt_kernel<<<8192, 256, 0, stream>>>(x, xb, 2097152);
  wtrans_kernel<<<dim3(16, 16), 256, 0, stream>>>(Wq, Wqt);
  wtrans_kernel<<<dim3(16, 16), 256, 0, stream>>>(Wk, Wkt);
  wtrans_kernel<<<dim3(16, 16), 256, 0, stream>>>(Wv, Wvt);
  wtrans_kernel<<<dim3(16, 16), 256, 0, stream>>>(Wo, Wot);
  gemm_kernel<0><<<dim3(64, 24), 256, 0, stream>>>(xb, Wqt, Qb, Kb, Vb, nullptr, nullptr,
                                                   8192, 3072, 1024);
  vtrans_kernel<<<dim3(32, 64), 256, 0, stream>>>(Vb, Vtb);
  attn_kernel<<<512, 512, 0, stream>>>(Qb, Kb, Vtb, ctxb);
  gemm_kernel<1><<<dim3(64, 8), 256, 0, stream>>>(ctxb, Wot, nullptr, nullptr, nullptr, out, bo,
                                                  8192, 1024, 1024);
}